// Round 1
// baseline (288.145 us; speedup 1.0000x reference)
//
#include <hip/hip_runtime.h>

#define C_CLUST 8
#define N_PAT   16384
#define D_FEAT  1024
#define DQ_DIM  128
#define K_TOP   128

// 1/sqrt(128) and 1/sqrt(1024)
#define INV_S128 0.08838834764831844055
#define INV_S1024 0.03125

// ---------- helpers ----------
__device__ inline unsigned f2key(float f) {
    unsigned u = __float_as_uint(f);
    return (u & 0x80000000u) ? ~u : (u | 0x80000000u);
}
__device__ inline float key2f(unsigned k) {
    unsigned u = (k & 0x80000000u) ? (k ^ 0x80000000u) : ~k;
    return __uint_as_float(u);
}

// ---------- kernel 1: per-cluster r = Wq @ qk (f64), b0 = bq . qk ----------
__global__ __launch_bounds__(128) void prep_kernel(
    const float* __restrict__ key_feats,  // [C,1,D]
    const float* __restrict__ Wq,         // [D,DQ]
    const float* __restrict__ bq,         // [DQ]
    double* __restrict__ r,               // [C][D]
    double* __restrict__ b0)              // [C]
{
    __shared__ float keyrow[D_FEAT];
    __shared__ double qk[DQ_DIM];
    const int c = blockIdx.x;
    const int tid = threadIdx.x;          // 128 threads

    for (int d = tid; d < D_FEAT; d += 128) keyrow[d] = key_feats[c * D_FEAT + d];
    __syncthreads();

    {   // qk[j] = key . Wq[:,j] + bq[j]
        double acc = 0.0;
        const int j = tid;
        for (int d = 0; d < D_FEAT; ++d)
            acc += (double)keyrow[d] * (double)Wq[d * DQ_DIM + j];
        qk[j] = acc + (double)bq[j];
    }
    __syncthreads();

    if (tid == 0) {
        double acc = 0.0;
        for (int j = 0; j < DQ_DIM; ++j) acc += (double)bq[j] * qk[j];
        b0[c] = acc;
    }
    for (int d = tid; d < D_FEAT; d += 128) {
        double acc = 0.0;
        for (int j = 0; j < DQ_DIM; ++j)
            acc += (double)Wq[d * DQ_DIM + j] * qk[j];
        r[c * D_FEAT + d] = acc;
    }
}

// ---------- kernel 2: scores[c][n] = feats[c,n,:] . r[c,:] + b0[c]  (wave per row) ----------
__global__ __launch_bounds__(256) void score_kernel(
    const float* __restrict__ feats,      // [C,N,D]
    const double* __restrict__ r,         // [C][D]
    const double* __restrict__ b0,        // [C]
    float* __restrict__ scores)           // [C][N]
{
    const int w    = blockIdx.x * 4 + (threadIdx.x >> 6); // global wave id = row id
    const int lane = threadIdx.x & 63;
    const int c = w >> 14;                 // 16384 rows per cluster
    const int n = w & (N_PAT - 1);

    const float4* fp = (const float4*)(feats + (size_t)(c * N_PAT + n) * D_FEAT);
    const double* rp = r + c * D_FEAT;

    double acc = 0.0;
#pragma unroll
    for (int it = 0; it < 4; ++it) {
        float4 f = fp[it * 64 + lane];
        int d = it * 256 + lane * 4;
        acc += (double)f.x * rp[d + 0];
        acc += (double)f.y * rp[d + 1];
        acc += (double)f.z * rp[d + 2];
        acc += (double)f.w * rp[d + 3];
    }
#pragma unroll
    for (int o = 32; o > 0; o >>= 1) acc += __shfl_xor(acc, o, 64);
    if (lane == 0) scores[c * N_PAT + n] = (float)(acc + b0[c]);
}

// ---------- kernel 3: per-cluster softmax stats + top-128 (sorted) + A_ weights ----------
__global__ __launch_bounds__(1024) void topk_kernel(
    const float* __restrict__ scores,     // [C][N]
    int* __restrict__ top_idx,            // [C][K]
    double* __restrict__ Aw)              // [C][K]
{
    const int c = blockIdx.x;
    const int tid = threadIdx.x;
    const int lane = tid & 63, wid = tid >> 6;

    __shared__ double   red_d[16];
    __shared__ unsigned red_u[16];
    __shared__ unsigned bcast_u;
    __shared__ double   bcast_d;
    __shared__ int cntG, cntE;
    __shared__ int idxG[K_TOP];
    __shared__ int idxE[256];
    __shared__ int list[K_TOP];
    __shared__ unsigned long long pairs[K_TOP];
    __shared__ double pd[K_TOP];
    __shared__ double red2[2];

    // 16 scores per thread, register-resident
    float sv[16];
    unsigned uk[16];
#pragma unroll
    for (int k = 0; k < 16; ++k) {
        sv[k] = scores[c * N_PAT + k * 1024 + tid];
        uk[k] = f2key(sv[k]);
    }

    // block max (on sortable keys == max score)
    unsigned mk = 0;
#pragma unroll
    for (int k = 0; k < 16; ++k) mk = max(mk, uk[k]);
#pragma unroll
    for (int o = 32; o > 0; o >>= 1) mk = max(mk, __shfl_xor(mk, o, 64));
    if (lane == 0) red_u[wid] = mk;
    __syncthreads();
    if (tid == 0) {
        unsigned m = 0;
        for (int i = 0; i < 16; ++i) m = max(m, red_u[i]);
        bcast_u = m;
    }
    __syncthreads();
    const double m_t = (double)key2f(bcast_u) * INV_S128;

    // Z = sum exp(s/sqrt(128) - m_t)
    double zs = 0.0;
#pragma unroll
    for (int k = 0; k < 16; ++k) zs += exp((double)sv[k] * INV_S128 - m_t);
#pragma unroll
    for (int o = 32; o > 0; o >>= 1) zs += __shfl_xor(zs, o, 64);
    __syncthreads();
    if (lane == 0) red_d[wid] = zs;
    __syncthreads();
    if (tid == 0) {
        double z = 0.0;
        for (int i = 0; i < 16; ++i) z += red_d[i];
        bcast_d = z;
    }
    __syncthreads();
    const double Z = bcast_d;

    // binary search: largest key T with count(key >= T) >= 128
    unsigned lo = 0u, hi = 0xFFFFFFFFu;
    while (lo < hi) {
        unsigned span = hi - lo;
        unsigned mid = lo + (span >> 1) + (span & 1u);   // ceil midpoint, >= lo+1
        unsigned cl = 0;
#pragma unroll
        for (int k = 0; k < 16; ++k) cl += (uk[k] >= mid) ? 1u : 0u;
#pragma unroll
        for (int o = 32; o > 0; o >>= 1) cl += __shfl_xor(cl, o, 64);
        __syncthreads();
        if (lane == 0) red_u[wid] = cl;
        __syncthreads();
        if (tid == 0) {
            unsigned s = 0;
            for (int i = 0; i < 16; ++i) s += red_u[i];
            bcast_u = s;
        }
        __syncthreads();
        if (bcast_u >= (unsigned)K_TOP) lo = mid; else hi = mid - 1;
    }

    // collect: key > lo definitely in; key == lo fills remainder by smallest index
    if (tid == 0) { cntG = 0; cntE = 0; }
    __syncthreads();
#pragma unroll
    for (int k = 0; k < 16; ++k) {
        int n = k * 1024 + tid;
        if (uk[k] > lo) {
            int p = atomicAdd(&cntG, 1);
            idxG[p] = n;                          // cntG < 128 guaranteed
        } else if (uk[k] == lo) {
            int p = atomicAdd(&cntE, 1);
            if (p < 256) idxE[p] = n;
        }
    }
    __syncthreads();
    const int nG = cntG;
    const int nE = min(cntE, 256);
    if (tid == 0) {                                // sort equal-key indices ascending
        for (int i = 1; i < nE; ++i) {
            int v = idxE[i]; int j = i - 1;
            while (j >= 0 && idxE[j] > v) { idxE[j + 1] = idxE[j]; --j; }
            idxE[j + 1] = v;
        }
    }
    __syncthreads();
    if (tid < K_TOP) list[tid] = (tid < nG) ? idxG[tid] : idxE[tid - nG];
    __syncthreads();

    // composite sort key: value desc, index asc  -> sort u64 descending
    if (tid < K_TOP) {
        int idx = list[tid];
        unsigned key = f2key(scores[c * N_PAT + idx]);
        pairs[tid] = ((unsigned long long)key << 32) | (unsigned)(~(unsigned)idx);
    }
    for (int size = 2; size <= K_TOP; size <<= 1) {
        for (int stride = size >> 1; stride > 0; stride >>= 1) {
            __syncthreads();
            if (tid < K_TOP) {
                int p = tid ^ stride;
                if (p > tid) {
                    unsigned long long a = pairs[tid], b = pairs[p];
                    bool desc = ((tid & size) == 0);
                    if (desc ? (a < b) : (a > b)) { pairs[tid] = b; pairs[p] = a; }
                }
            }
        }
    }
    __syncthreads();

    // top_vals p_i and A_ = softmax(p/32)
    if (tid < K_TOP) {
        unsigned long long pr = pairs[tid];
        unsigned key = (unsigned)(pr >> 32);
        int idx = (int)(~(unsigned)(pr & 0xFFFFFFFFull));
        top_idx[c * K_TOP + tid] = idx;
        double s = (double)key2f(key);
        pd[tid] = exp(s * INV_S128 - m_t) / Z;
    }
    __syncthreads();
    if (tid < K_TOP) {
        double e = exp((pd[tid] - pd[0]) * INV_S1024);   // pd[0] is the max (sorted)
        double se = e;
#pragma unroll
        for (int o = 32; o > 0; o >>= 1) se += __shfl_xor(se, o, 64);
        if (lane == 0) red2[wid] = se;
    }
    __syncthreads();
    if (tid < K_TOP) {
        double tot = red2[0] + red2[1];
        double e = exp((pd[tid] - pd[0]) * INV_S1024);
        Aw[c * K_TOP + tid] = e / tot;
    }
}

// ---------- kernel 4: gather selected rows to output ----------
__global__ __launch_bounds__(256) void gather_kernel(
    const float* __restrict__ feats,
    const int* __restrict__ top_idx,
    float* __restrict__ out)              // [C*K, D]
{
    const int b = blockIdx.x;              // c*K + rank
    const int c = b >> 7;
    const int row = top_idx[b];
    const float4* src = (const float4*)(feats + (size_t)(c * N_PAT + row) * D_FEAT);
    float4* dst = (float4*)(out + (size_t)b * D_FEAT);
    dst[threadIdx.x] = src[threadIdx.x];   // 256 threads * float4 = 1024 floats
}

// ---------- kernel 5: w[c][d] = sum_i A_[i] * feats[c, idx_i, d] ----------
__global__ __launch_bounds__(128) void wsum_kernel(
    const float* __restrict__ feats,
    const int* __restrict__ top_idx,
    const double* __restrict__ Aw,
    double* __restrict__ w)               // [C][D]
{
    __shared__ int sidx[K_TOP];
    __shared__ double sa[K_TOP];
    const int b = blockIdx.x;              // c*8 + chunk
    const int c = b >> 3, chunk = b & 7;
    const int tid = threadIdx.x;           // 128
    sidx[tid] = top_idx[c * K_TOP + tid];
    sa[tid] = Aw[c * K_TOP + tid];
    __syncthreads();
    const int d = chunk * 128 + tid;
    double acc = 0.0;
    for (int i = 0; i < K_TOP; ++i)
        acc += sa[i] * (double)feats[(size_t)(c * N_PAT + sidx[i]) * D_FEAT + d];
    w[c * D_FEAT + d] = acc;
}

// ---------- kernel 6: fusion[c][d'] = w[c,:] @ Wv[:,d'] + bv[d'] ----------
__global__ __launch_bounds__(256) void fusion_kernel(
    const double* __restrict__ w,         // [C][D]
    const float* __restrict__ Wv,         // [D,D]
    const float* __restrict__ bv,         // [D]
    float* __restrict__ out)              // fusion at offset C*K*D
{
    const int t = blockIdx.x * 256 + threadIdx.x;   // 0..8191
    const int c = t >> 10, dp = t & 1023;
    const double* wc = w + c * D_FEAT;
    double acc = (double)bv[dp];
    for (int d = 0; d < D_FEAT; ++d)
        acc += wc[d] * (double)Wv[d * D_FEAT + dp];
    out[(size_t)(C_CLUST * K_TOP * D_FEAT) + t] = (float)acc;
}

extern "C" void kernel_launch(void* const* d_in, const int* in_sizes, int n_in,
                              void* d_out, int out_size, void* d_ws, size_t ws_size,
                              hipStream_t stream) {
    const float* feats     = (const float*)d_in[0];  // [8,16384,1024]
    const float* key_feats = (const float*)d_in[1];  // [8,1,1024]
    const float* Wq        = (const float*)d_in[2];  // [1024,128]
    const float* bq        = (const float*)d_in[3];  // [128]
    const float* Wv        = (const float*)d_in[4];  // [1024,1024]
    const float* bv        = (const float*)d_in[5];  // [1024]
    float* out = (float*)d_out;

    char* ws = (char*)d_ws;
    float*  scores  = (float*)(ws + 0);        // 8*16384*4   = 524288
    double* r       = (double*)(ws + 524288);  // 8*1024*8    = 65536
    double* b0      = (double*)(ws + 589824);  // 8*8         = 64
    int*    top_idx = (int*)(ws + 589888);     // 8*128*4     = 4096
    double* Aw      = (double*)(ws + 593984);  // 8*128*8     = 8192
    double* w       = (double*)(ws + 602176);  // 8*1024*8    = 65536  (end 667712)

    hipLaunchKernelGGL(prep_kernel,   dim3(C_CLUST), dim3(128),  0, stream, key_feats, Wq, bq, r, b0);
    hipLaunchKernelGGL(score_kernel,  dim3(32768),   dim3(256),  0, stream, feats, r, b0, scores);
    hipLaunchKernelGGL(topk_kernel,   dim3(C_CLUST), dim3(1024), 0, stream, scores, top_idx, Aw);
    hipLaunchKernelGGL(gather_kernel, dim3(C_CLUST * K_TOP), dim3(256), 0, stream, feats, top_idx, out);
    hipLaunchKernelGGL(wsum_kernel,   dim3(C_CLUST * 8), dim3(128), 0, stream, feats, top_idx, Aw, w);
    hipLaunchKernelGGL(fusion_kernel, dim3(32),      dim3(256),  0, stream, w, Wv, bv, out);
}

// Round 2
// 267.307 us; speedup vs baseline: 1.0780x; 1.0780x over previous
//
#include <hip/hip_runtime.h>

#define C_CLUST 8
#define N_PAT   16384
#define D_FEAT  1024
#define DQ_DIM  128
#define K_TOP   128

// 1/sqrt(128) and 1/sqrt(1024)
#define INV_S128 0.08838834764831844055
#define INV_S1024 0.03125

// ---------- helpers ----------
__device__ inline unsigned f2key(float f) {
    unsigned u = __float_as_uint(f);
    return (u & 0x80000000u) ? ~u : (u | 0x80000000u);
}
__device__ inline float key2f(unsigned k) {
    unsigned u = (k & 0x80000000u) ? (k ^ 0x80000000u) : ~k;
    return __uint_as_float(u);
}

// ---------- kernel 1a: qk[c][j] = key_c . Wq[:,j] + bq[j] (f64); b0[c] = bq . qk ----------
__global__ __launch_bounds__(1024) void qk_kernel(
    const float* __restrict__ key_feats,  // [C,1,D]
    const float* __restrict__ Wq,         // [D,DQ]
    const float* __restrict__ bq,         // [DQ]
    double* __restrict__ qk,              // [C][DQ]
    double* __restrict__ b0)              // [C]
{
    __shared__ float keyrow[D_FEAT];
    __shared__ double part[8][DQ_DIM];
    const int c = blockIdx.x;
    const int tid = threadIdx.x;           // 1024 threads

    keyrow[tid] = key_feats[c * D_FEAT + tid];
    __syncthreads();

    const int j = tid & 127, s = tid >> 7; // 8-way split over d
    double acc = 0.0;
    for (int d = s; d < D_FEAT; d += 8)    // coalesced: 128 consecutive j per d
        acc += (double)keyrow[d] * (double)Wq[d * DQ_DIM + j];
    part[s][j] = acc;
    __syncthreads();

    if (tid < DQ_DIM) {
        double v = part[0][tid];
#pragma unroll
        for (int s2 = 1; s2 < 8; ++s2) v += part[s2][tid];
        v += (double)bq[tid];
        qk[c * DQ_DIM + tid] = v;
        part[0][tid] = (double)bq[tid] * v;
    }
    __syncthreads();
    if (tid == 0) {
        double acc2 = 0.0;
        for (int i = 0; i < DQ_DIM; ++i) acc2 += part[0][i];
        b0[c] = acc2;
    }
}

// ---------- kernel 1b: r[c][d] = Wq[d,:] . qk[c,:]  (one wave per (c,d)) ----------
__global__ __launch_bounds__(256) void r_kernel(
    const float* __restrict__ Wq,         // [D,DQ]
    const double* __restrict__ qk,        // [C][DQ]
    double* __restrict__ r)               // [C][D]
{
    const int w = blockIdx.x * 4 + (threadIdx.x >> 6);
    const int lane = threadIdx.x & 63;
    const int c = w >> 10, d = w & (D_FEAT - 1);
    double q0 = qk[c * DQ_DIM + lane];
    double q1 = qk[c * DQ_DIM + 64 + lane];
    double acc = (double)Wq[d * DQ_DIM + lane] * q0
               + (double)Wq[d * DQ_DIM + 64 + lane] * q1;
#pragma unroll
    for (int o = 32; o > 0; o >>= 1) acc += __shfl_xor(acc, o, 64);
    if (lane == 0) r[c * D_FEAT + d] = acc;
}

// ---------- kernel 2: scores[c][n] = feats[c,n,:] . r[c,:] + b0[c]  (wave per row) ----------
__global__ __launch_bounds__(256) void score_kernel(
    const float* __restrict__ feats,      // [C,N,D]
    const double* __restrict__ r,         // [C][D]
    const double* __restrict__ b0,        // [C]
    float* __restrict__ scores)           // [C][N]
{
    const int w    = blockIdx.x * 4 + (threadIdx.x >> 6); // global wave id = row id
    const int lane = threadIdx.x & 63;
    const int c = w >> 14;                 // 16384 rows per cluster
    const int n = w & (N_PAT - 1);

    const float4* fp = (const float4*)(feats + (size_t)(c * N_PAT + n) * D_FEAT);
    const double* rp = r + c * D_FEAT;

    double acc = 0.0;
#pragma unroll
    for (int it = 0; it < 4; ++it) {
        float4 f = fp[it * 64 + lane];
        int d = it * 256 + lane * 4;
        acc += (double)f.x * rp[d + 0];
        acc += (double)f.y * rp[d + 1];
        acc += (double)f.z * rp[d + 2];
        acc += (double)f.w * rp[d + 3];
    }
#pragma unroll
    for (int o = 32; o > 0; o >>= 1) acc += __shfl_xor(acc, o, 64);
    if (lane == 0) scores[c * N_PAT + n] = (float)(acc + b0[c]);
}

// ---------- kernel 3: per-cluster softmax stats + top-128 (sorted) + A_ weights ----------
__global__ __launch_bounds__(1024) void topk_kernel(
    const float* __restrict__ scores,     // [C][N]
    int* __restrict__ top_idx,            // [C][K]
    double* __restrict__ Aw)              // [C][K]
{
    const int c = blockIdx.x;
    const int tid = threadIdx.x;
    const int lane = tid & 63, wid = tid >> 6;

    __shared__ double   red_d[16];
    __shared__ unsigned red_u[16];
    __shared__ unsigned bcast_u;
    __shared__ double   bcast_d;
    __shared__ int cntG, cntE;
    __shared__ int idxG[K_TOP];
    __shared__ int idxE[256];
    __shared__ int list[K_TOP];
    __shared__ unsigned long long pairs[K_TOP];
    __shared__ double pd[K_TOP];
    __shared__ double red2[2];

    // 16 scores per thread, register-resident
    float sv[16];
    unsigned uk[16];
#pragma unroll
    for (int k = 0; k < 16; ++k) {
        sv[k] = scores[c * N_PAT + k * 1024 + tid];
        uk[k] = f2key(sv[k]);
    }

    // block max (on sortable keys == max score)
    unsigned mk = 0;
#pragma unroll
    for (int k = 0; k < 16; ++k) mk = max(mk, uk[k]);
#pragma unroll
    for (int o = 32; o > 0; o >>= 1) mk = max(mk, __shfl_xor(mk, o, 64));
    if (lane == 0) red_u[wid] = mk;
    __syncthreads();
    if (tid == 0) {
        unsigned m = 0;
        for (int i = 0; i < 16; ++i) m = max(m, red_u[i]);
        bcast_u = m;
    }
    __syncthreads();
    const double m_t = (double)key2f(bcast_u) * INV_S128;

    // Z = sum exp(s/sqrt(128) - m_t)
    double zs = 0.0;
#pragma unroll
    for (int k = 0; k < 16; ++k) zs += exp((double)sv[k] * INV_S128 - m_t);
#pragma unroll
    for (int o = 32; o > 0; o >>= 1) zs += __shfl_xor(zs, o, 64);
    __syncthreads();
    if (lane == 0) red_d[wid] = zs;
    __syncthreads();
    if (tid == 0) {
        double z = 0.0;
        for (int i = 0; i < 16; ++i) z += red_d[i];
        bcast_d = z;
    }
    __syncthreads();
    const double Z = bcast_d;

    // binary search: largest key T with count(key >= T) >= 128
    unsigned lo = 0u, hi = 0xFFFFFFFFu;
    while (lo < hi) {
        unsigned span = hi - lo;
        unsigned mid = lo + (span >> 1) + (span & 1u);   // ceil midpoint, >= lo+1
        unsigned cl = 0;
#pragma unroll
        for (int k = 0; k < 16; ++k) cl += (uk[k] >= mid) ? 1u : 0u;
#pragma unroll
        for (int o = 32; o > 0; o >>= 1) cl += __shfl_xor(cl, o, 64);
        __syncthreads();
        if (lane == 0) red_u[wid] = cl;
        __syncthreads();
        if (tid == 0) {
            unsigned s = 0;
            for (int i = 0; i < 16; ++i) s += red_u[i];
            bcast_u = s;
        }
        __syncthreads();
        if (bcast_u >= (unsigned)K_TOP) lo = mid; else hi = mid - 1;
    }

    // collect: key > lo definitely in; key == lo fills remainder by smallest index
    if (tid == 0) { cntG = 0; cntE = 0; }
    __syncthreads();
#pragma unroll
    for (int k = 0; k < 16; ++k) {
        int n = k * 1024 + tid;
        if (uk[k] > lo) {
            int p = atomicAdd(&cntG, 1);
            idxG[p] = n;                          // cntG < 128 guaranteed
        } else if (uk[k] == lo) {
            int p = atomicAdd(&cntE, 1);
            if (p < 256) idxE[p] = n;
        }
    }
    __syncthreads();
    const int nG = cntG;
    const int nE = min(cntE, 256);
    if (tid == 0) {                                // sort equal-key indices ascending
        for (int i = 1; i < nE; ++i) {
            int v = idxE[i]; int j = i - 1;
            while (j >= 0 && idxE[j] > v) { idxE[j + 1] = idxE[j]; --j; }
            idxE[j + 1] = v;
        }
    }
    __syncthreads();
    if (tid < K_TOP) list[tid] = (tid < nG) ? idxG[tid] : idxE[tid - nG];
    __syncthreads();

    // composite sort key: value desc, index asc  -> sort u64 descending
    if (tid < K_TOP) {
        int idx = list[tid];
        unsigned key = f2key(scores[c * N_PAT + idx]);
        pairs[tid] = ((unsigned long long)key << 32) | (unsigned)(~(unsigned)idx);
    }
    for (int size = 2; size <= K_TOP; size <<= 1) {
        for (int stride = size >> 1; stride > 0; stride >>= 1) {
            __syncthreads();
            if (tid < K_TOP) {
                int p = tid ^ stride;
                if (p > tid) {
                    unsigned long long a = pairs[tid], b = pairs[p];
                    bool desc = ((tid & size) == 0);
                    if (desc ? (a < b) : (a > b)) { pairs[tid] = b; pairs[p] = a; }
                }
            }
        }
    }
    __syncthreads();

    // top_vals p_i and A_ = softmax(p/32)
    if (tid < K_TOP) {
        unsigned long long pr = pairs[tid];
        unsigned key = (unsigned)(pr >> 32);
        int idx = (int)(~(unsigned)(pr & 0xFFFFFFFFull));
        top_idx[c * K_TOP + tid] = idx;
        double s = (double)key2f(key);
        pd[tid] = exp(s * INV_S128 - m_t) / Z;
    }
    __syncthreads();
    if (tid < K_TOP) {
        double e = exp((pd[tid] - pd[0]) * INV_S1024);   // pd[0] is the max (sorted)
        double se = e;
#pragma unroll
        for (int o = 32; o > 0; o >>= 1) se += __shfl_xor(se, o, 64);
        if (lane == 0) red2[wid] = se;
    }
    __syncthreads();
    if (tid < K_TOP) {
        double tot = red2[0] + red2[1];
        double e = exp((pd[tid] - pd[0]) * INV_S1024);
        Aw[c * K_TOP + tid] = e / tot;
    }
}

// ---------- kernel 4: gather selected rows to output ----------
__global__ __launch_bounds__(256) void gather_kernel(
    const float* __restrict__ feats,
    const int* __restrict__ top_idx,
    float* __restrict__ out)              // [C*K, D]
{
    const int b = blockIdx.x;              // c*K + rank
    const int c = b >> 7;
    const int row = top_idx[b];
    const float4* src = (const float4*)(feats + (size_t)(c * N_PAT + row) * D_FEAT);
    float4* dst = (float4*)(out + (size_t)b * D_FEAT);
    dst[threadIdx.x] = src[threadIdx.x];   // 256 threads * float4 = 1024 floats
}

// ---------- kernel 5: w[c][d] = sum_i A_[i] * feats[c, idx_i, d] ----------
__global__ __launch_bounds__(128) void wsum_kernel(
    const float* __restrict__ feats,
    const int* __restrict__ top_idx,
    const double* __restrict__ Aw,
    double* __restrict__ w)               // [C][D]
{
    __shared__ int sidx[K_TOP];
    __shared__ double sa[K_TOP];
    const int b = blockIdx.x;              // c*8 + chunk
    const int c = b >> 3, chunk = b & 7;
    const int tid = threadIdx.x;           // 128
    sidx[tid] = top_idx[c * K_TOP + tid];
    sa[tid] = Aw[c * K_TOP + tid];
    __syncthreads();
    const int d = chunk * 128 + tid;
    double acc = 0.0;
    for (int i = 0; i < K_TOP; ++i)
        acc += sa[i] * (double)feats[(size_t)(c * N_PAT + sidx[i]) * D_FEAT + d];
    w[c * D_FEAT + d] = acc;
}

// ---------- kernel 6: fusion[c][d'] = w[c,:] @ Wv[:,d'] + bv[d'] ----------
__global__ __launch_bounds__(256) void fusion_kernel(
    const double* __restrict__ w,         // [C][D]
    const float* __restrict__ Wv,         // [D,D]
    const float* __restrict__ bv,         // [D]
    float* __restrict__ out)              // fusion at offset C*K*D
{
    const int t = blockIdx.x * 256 + threadIdx.x;   // 0..8191
    const int c = t >> 10, dp = t & 1023;
    const double* wc = w + c * D_FEAT;
    double acc = (double)bv[dp];
    for (int d = 0; d < D_FEAT; ++d)
        acc += wc[d] * (double)Wv[d * D_FEAT + dp];
    out[(size_t)(C_CLUST * K_TOP * D_FEAT) + t] = (float)acc;
}

extern "C" void kernel_launch(void* const* d_in, const int* in_sizes, int n_in,
                              void* d_out, int out_size, void* d_ws, size_t ws_size,
                              hipStream_t stream) {
    const float* feats     = (const float*)d_in[0];  // [8,16384,1024]
    const float* key_feats = (const float*)d_in[1];  // [8,1,1024]
    const float* Wq        = (const float*)d_in[2];  // [1024,128]
    const float* bq        = (const float*)d_in[3];  // [128]
    const float* Wv        = (const float*)d_in[4];  // [1024,1024]
    const float* bv        = (const float*)d_in[5];  // [1024]
    float* out = (float*)d_out;

    char* ws = (char*)d_ws;
    float*  scores  = (float*)(ws + 0);        // 8*16384*4   = 524288
    double* r       = (double*)(ws + 524288);  // 8*1024*8    = 65536
    double* b0      = (double*)(ws + 589824);  // 8*8         = 64
    int*    top_idx = (int*)(ws + 589888);     // 8*128*4     = 4096
    double* Aw      = (double*)(ws + 593984);  // 8*128*8     = 8192
    double* w       = (double*)(ws + 602176);  // 8*1024*8    = 65536
    double* qk      = (double*)(ws + 667712);  // 8*128*8     = 8192   (end 675904)

    hipLaunchKernelGGL(qk_kernel,     dim3(C_CLUST), dim3(1024), 0, stream, key_feats, Wq, bq, qk, b0);
    hipLaunchKernelGGL(r_kernel,      dim3(C_CLUST * D_FEAT / 4), dim3(256), 0, stream, Wq, qk, r);
    hipLaunchKernelGGL(score_kernel,  dim3(32768),   dim3(256),  0, stream, feats, r, b0, scores);
    hipLaunchKernelGGL(topk_kernel,   dim3(C_CLUST), dim3(1024), 0, stream, scores, top_idx, Aw);
    hipLaunchKernelGGL(gather_kernel, dim3(C_CLUST * K_TOP), dim3(256), 0, stream, feats, top_idx, out);
    hipLaunchKernelGGL(wsum_kernel,   dim3(C_CLUST * 8), dim3(128), 0, stream, feats, top_idx, Aw, w);
    hipLaunchKernelGGL(fusion_kernel, dim3(32),      dim3(256),  0, stream, w, Wv, bv, out);
}